// Round 8
// baseline (247.486 us; speedup 1.0000x reference)
//
#include <hip/hip_runtime.h>

#define DIM 2048
#define KROWS 4

typedef unsigned int uint2v __attribute__((ext_vector_type(2)));

#define BFLY(a, b) { float _t = (a); (a) = _t + (b); (b) = _t - (b); }

__device__ __forceinline__ void bf4_pair(float4 &a, float4 &b) {
  BFLY(a.x, b.x); BFLY(a.y, b.y); BFLY(a.z, b.z); BFLY(a.w, b.w);
}

// Butterfly element-index bits 0 and 1 (within the float4 components).
__device__ __forceinline__ void bf_comps(float4 &a) {
  BFLY(a.x, a.y); BFLY(a.z, a.w);   // bit 0
  BFLY(a.x, a.z); BFLY(a.y, a.w);   // bit 1
}

// Butterfly all 3 bits of the 8-register index (strides 1,2,4).
__device__ __forceinline__ void bf_oct(float4 v[8]) {
  bf4_pair(v[0], v[1]); bf4_pair(v[2], v[3]);
  bf4_pair(v[4], v[5]); bf4_pair(v[6], v[7]);
  bf4_pair(v[0], v[2]); bf4_pair(v[1], v[3]);
  bf4_pair(v[4], v[6]); bf4_pair(v[5], v[7]);
  bf4_pair(v[0], v[4]); bf4_pair(v[1], v[5]);
  bf4_pair(v[2], v[6]); bf4_pair(v[3], v[7]);
}

// Butterfly only reg-index bits 0,1 (strides 1,2).
__device__ __forceinline__ void bf_oct12(float4 v[8]) {
  bf4_pair(v[0], v[1]); bf4_pair(v[2], v[3]);
  bf4_pair(v[4], v[5]); bf4_pair(v[6], v[7]);
  bf4_pair(v[0], v[2]); bf4_pair(v[1], v[3]);
  bf4_pair(v[4], v[6]); bf4_pair(v[5], v[7]);
}

// Cross-lane butterfly on lane bit 0 / 1 via DPP quad_perm (VALU rate).
// 0xB1 = [1,0,3,2] (xor1), 0x4E = [2,3,0,1] (xor2).
template <int CTRL>
__device__ __forceinline__ float dpp_mov(float x) {
  return __int_as_float(
      __builtin_amdgcn_mov_dpp(__float_as_int(x), CTRL, 0xF, 0xF, true));
}

template <int CTRL>
__device__ __forceinline__ void dpp_stage(float4 v[8], float sgn) {
  #pragma unroll
  for (int i = 0; i < 8; ++i) {
    float px = dpp_mov<CTRL>(v[i].x);
    float py = dpp_mov<CTRL>(v[i].y);
    float pz = dpp_mov<CTRL>(v[i].z);
    float pw = dpp_mov<CTRL>(v[i].w);
    // lane with bit clear: x + partner ; lane with bit set: partner - x
    v[i].x = fmaf(sgn, v[i].x, px);
    v[i].y = fmaf(sgn, v[i].y, py);
    v[i].z = fmaf(sgn, v[i].z, pz);
    v[i].w = fmaf(sgn, v[i].w, pw);
  }
}

// Cross-lane butterfly on lane bit 4 via v_permlane16_swap_b32 (VALU rate,
// gfx950, harness-verified round 6): r[0]=x[lane&~16], r[1]=x[lane|16].
__device__ __forceinline__ float pl16_bfly(float x, float sgn) {
  uint2v r = __builtin_amdgcn_permlane16_swap(
      __float_as_uint(x), __float_as_uint(x), false, false);
  return fmaf(sgn, __uint_as_float(r[1]), __uint_as_float(r[0]));
}

__device__ __forceinline__ void pl16_stage(float4 v[8], float sgn) {
  #pragma unroll
  for (int i = 0; i < 8; ++i) {
    v[i].x = pl16_bfly(v[i].x, sgn);
    v[i].y = pl16_bfly(v[i].y, sgn);
    v[i].z = pl16_bfly(v[i].z, sgn);
    v[i].w = pl16_bfly(v[i].w, sgn);
  }
}

// Cross-lane butterfly on lane bit 5 via v_permlane32_swap_b32 (VALU rate,
// harness-verified): r[0]=x[lane&~32], r[1]=x[lane|32].
__device__ __forceinline__ float pl32_bfly(float x, float sgn) {
  uint2v r = __builtin_amdgcn_permlane32_swap(
      __float_as_uint(x), __float_as_uint(x), false, false);
  return fmaf(sgn, __uint_as_float(r[1]), __uint_as_float(r[0]));
}

__device__ __forceinline__ void pl32_stage(float4 v[8], float sgn) {
  #pragma unroll
  for (int i = 0; i < 8; ++i) {
    v[i].x = pl32_bfly(v[i].x, sgn);
    v[i].y = pl32_bfly(v[i].y, sgn);
    v[i].z = pl32_bfly(v[i].z, sgn);
    v[i].w = pl32_bfly(v[i].w, sgn);
  }
}

// Wave-local LDS ordering (slice is wave-private; no workgroup barrier).
__device__ __forceinline__ void lds_fence() {
  asm volatile("s_waitcnt lgkmcnt(0)" ::: "memory");
}

// Packed-bit sign flip: bit (base+j) of p holds the sign bit for comp j.
// (p << (31-k)) & 0x8000'0000 reproduces the exact +-1 sign mask.
__device__ __forceinline__ void sflip4(float4 &a, unsigned p, int base) {
  a.x = __uint_as_float(__float_as_uint(a.x) ^ ((p << (31 - (base + 0))) & 0x80000000u));
  a.y = __uint_as_float(__float_as_uint(a.y) ^ ((p << (31 - (base + 1))) & 0x80000000u));
  a.z = __uint_as_float(__float_as_uint(a.z) ^ ((p << (31 - (base + 2))) & 0x80000000u));
  a.w = __uint_as_float(__float_as_uint(a.w) ^ ((p << (31 - (base + 3))) & 0x80000000u));
}

// Block exchange: element bits [4,5] (lane bits 2,3) <-> [8,9] (reg bits
// 0,1). Involution. Same per-half index mapping as the harness-verified
// round-6 version, but the two reg-halves now use DISJOINT 4 KiB windows
// (W0, W1) so all 16 writes issue before one fence, then all 16 reads.
__device__ __forceinline__ void xchg(float4* __restrict__ W0,
                                     float4* __restrict__ W1,
                                     float4 v[8], int lane) {
  const int m  = (lane >> 2) & 3;     // source reg-within-half
  const int ls = lane & ~12;          // lane with bits 2,3 cleared
  #pragma unroll
  for (int c2 = 0; c2 < 4; ++c2)
    W0[c2 * 64 + (lane ^ ((c2 & 1) << 2))] = v[c2];
  #pragma unroll
  for (int c2 = 0; c2 < 4; ++c2)
    W1[c2 * 64 + (lane ^ ((c2 & 1) << 2))] = v[4 + c2];
  lds_fence();
  #pragma unroll
  for (int c2 = 0; c2 < 4; ++c2)
    v[c2] = W0[m * 64 + ((ls | (c2 << 2)) ^ ((m & 1) << 2))];
  #pragma unroll
  for (int c2 = 0; c2 < 4; ++c2)
    v[4 + c2] = W1[m * 64 + ((ls | (c2 << 2)) ^ ((m & 1) << 2))];
  lds_fence();   // drain reads before the windows are overwritten again
}

// One wave per KROWS consecutive 2048-float rows, software-pipelined:
// next row's 8 dwordx4 loads issue before current row's compute, hiding
// HBM latency; signs are packed to 2 scalar bit-words ONCE per wave
// (natural layout for pass 1, T layout for pass 2) so the per-row chain
// has zero sign loads. Bit plan per pass (layout N: e = c*256+lane*4+r):
//   e0,e1 comps | e2,e3 DPP | e6 pl16 | e7 pl32 | e8,e9,e10 regs |
//   e4,e5 via one b128 LDS block-exchange (xchg) per pass.
__global__ __launch_bounds__(256) void srht2_kernel(
    const float* __restrict__ x, const int* __restrict__ signs,
    float* __restrict__ out, int nrows) {
  __shared__ __align__(16) float4 lds[8][256];   // 2 x 4 KiB per wave
  const int lane = threadIdx.x & 63;
  const int wv   = threadIdx.x >> 6;
  const int row0 = (blockIdx.x * 4 + wv) * KROWS;
  if (row0 >= nrows) return;

  float4* __restrict__ W0 = lds[wv * 2];
  float4* __restrict__ W1 = lds[wv * 2 + 1];

  const float sgn1  = (lane & 1)  ? -1.0f : 1.0f;
  const float sgn2  = (lane & 2)  ? -1.0f : 1.0f;
  const float sgn16 = (lane & 16) ? -1.0f : 1.0f;
  const float sgn32 = (lane & 32) ? -1.0f : 1.0f;

  const uint4* __restrict__ s0 = (const uint4*)signs;
  const uint4* __restrict__ s1 = (const uint4*)(signs + DIM);

  // ---- pack sign bits once per wave: bit 4c+j = sign of comp j of the
  // lane's c-th fragment. ps0: natural layout. ps1: T layout (the same
  // addressing the harness-verified round-6 pass 2 used).
  unsigned ps0 = 0, ps1 = 0;
  const int sb = (lane & 3) | ((lane >> 4) << 4) | (((lane >> 2) & 3) << 6);
  #pragma unroll
  for (int c = 0; c < 8; ++c) {
    uint4 s = s0[c * 64 + lane];
    ps0 |= (s.x >> 31) << (4 * c)     | (s.y >> 31) << (4 * c + 1)
        |  (s.z >> 31) << (4 * c + 2) | (s.w >> 31) << (4 * c + 3);
    uint4 t = s1[sb + ((c & 3) << 2) + ((c >> 2) << 8)];
    ps1 |= (t.x >> 31) << (4 * c)     | (t.y >> 31) << (4 * c + 1)
        |  (t.z >> 31) << (4 * c + 2) | (t.w >> 31) << (4 * c + 3);
  }

  const float4* __restrict__ xr   = (const float4*)(x + (size_t)row0 * DIM);
  float4*       __restrict__ orow = (float4*)(out + (size_t)row0 * DIM);

  float4 v[8], p[8];
  #pragma unroll
  for (int c = 0; c < 8; ++c) v[c] = xr[c * 64 + lane];

  #pragma unroll 1
  for (int k = 0; k < KROWS; ++k) {
    // prefetch next row (wave-uniform branch); latency hides under compute
    if (k + 1 < KROWS) {
      const float4* __restrict__ xrn = xr + (DIM / 4);
      #pragma unroll
      for (int c = 0; c < 8; ++c) p[c] = xrn[c * 64 + lane];
    }

    // ---- pass 1 (layout N) ----
    #pragma unroll
    for (int c = 0; c < 8; ++c) { sflip4(v[c], ps0, 4 * c); bf_comps(v[c]); }
    dpp_stage<0xB1>(v, sgn1);                     // e2
    dpp_stage<0x4E>(v, sgn2);                     // e3
    pl16_stage(v, sgn16);                         // e6
    pl32_stage(v, sgn32);                         // e7
    bf_oct(v);                                    // e8,e9,e10
    xchg(W0, W1, v, lane);                        // N -> T
    bf_oct12(v);                                  // e4,e5 (reg bits 0,1)

    // ---- pass 2 (layout T) ----
    #pragma unroll
    for (int c = 0; c < 8; ++c) { sflip4(v[c], ps1, 4 * c); bf_comps(v[c]); }
    dpp_stage<0xB1>(v, sgn1);                     // e2
    dpp_stage<0x4E>(v, sgn2);                     // e3
    pl16_stage(v, sgn16);                         // e6
    pl32_stage(v, sgn32);                         // e7
    bf_oct(v);                                    // e4,e5 (str 1,2) + e10
    xchg(W0, W1, v, lane);                        // T -> N
    bf_oct12(v);                                  // e8,e9 (reg bits 0,1)

    // ---- scale (exact pow2) and coalesced store ----
    const float sc = 1.0f / 2048.0f;
    #pragma unroll
    for (int c = 0; c < 8; ++c) {
      float4 t = v[c];
      t.x *= sc; t.y *= sc; t.z *= sc; t.w *= sc;
      orow[c * 64 + lane] = t;
    }

    if (k + 1 < KROWS) {
      #pragma unroll
      for (int c = 0; c < 8; ++c) v[c] = p[c];    // waits on p-loads only
      xr   += DIM / 4;
      orow += DIM / 4;
    }
  }
}

extern "C" void kernel_launch(void* const* d_in, const int* in_sizes, int n_in,
                              void* d_out, int out_size, void* d_ws, size_t ws_size,
                              hipStream_t stream) {
  const float* x     = (const float*)d_in[0];
  const int*   signs = (const int*)d_in[1];
  float*       out   = (float*)d_out;
  const int nrows   = in_sizes[0] / DIM;           // 16384
  const int nblocks = nrows / (4 * KROWS);         // 4 waves x KROWS rows
  hipLaunchKernelGGL(srht2_kernel, dim3(nblocks), dim3(256), 0, stream,
                     x, signs, out, nrows);
}